// Round 4
// baseline (624.947 us; speedup 1.0000x reference)
//
#include <hip/hip_runtime.h>
#include <hip/hip_cooperative_groups.h>

namespace cg = cooperative_groups;

#define BB 32
#define HH 1024
#define LL 128
#define TT 127
#define VV 32000
#define NT 255  // LL+TT

typedef __attribute__((ext_vector_type(8))) short bf16x8;
typedef __attribute__((ext_vector_type(4))) float f32x4;

#define MFMA(a, b, c) __builtin_amdgcn_mfma_f32_16x16x32_bf16((a), (b), (c), 0, 0, 0)

static __device__ __forceinline__ short f2bf(float f) {
  unsigned u = __builtin_bit_cast(unsigned, f);
  u += 0x7fffu + ((u >> 16) & 1u);   // round-to-nearest-even
  return (short)(u >> 16);
}

static __device__ __forceinline__ bf16x8 load_cvt8(const float* __restrict__ p) {
  f32x4 a = *(const f32x4*)p;
  f32x4 b = *(const f32x4*)(p + 4);
  bf16x8 r;
  r[0]=f2bf(a[0]); r[1]=f2bf(a[1]); r[2]=f2bf(a[2]); r[3]=f2bf(a[3]);
  r[4]=f2bf(b[0]); r[5]=f2bf(b[1]); r[6]=f2bf(b[2]); r[7]=f2bf(b[3]);
  return r;
}

static __device__ __forceinline__ bf16x8 load_add_cvt8(const float* __restrict__ p,
                                                       const float* __restrict__ q) {
  f32x4 a = *(const f32x4*)p, a2 = *(const f32x4*)(p + 4);
  f32x4 b = *(const f32x4*)q, b2 = *(const f32x4*)(q + 4);
  bf16x8 r;
  r[0]=f2bf(a[0]+b[0]); r[1]=f2bf(a[1]+b[1]); r[2]=f2bf(a[2]+b[2]); r[3]=f2bf(a[3]+b[3]);
  r[4]=f2bf(a2[0]+b2[0]); r[5]=f2bf(a2[1]+b2[1]); r[6]=f2bf(a2[2]+b2[2]); r[7]=f2bf(a2[3]+b2[3]);
  return r;
}

// sum of 4 K-partial context buffers (pctx[p][b][1024]) -> bf16x8 at col..col+7
static __device__ __forceinline__ bf16x8 sum4_cvt8(const float* __restrict__ pctx,
                                                   int b, int col) {
  const float* p = pctx + (size_t)b * HH + col;
  f32x4 a0 = *(const f32x4*)p,           a1 = *(const f32x4*)(p + 4);
  f32x4 b0 = *(const f32x4*)(p + 32768), b1 = *(const f32x4*)(p + 32772);
  f32x4 c0 = *(const f32x4*)(p + 65536), c1 = *(const f32x4*)(p + 65540);
  f32x4 d0 = *(const f32x4*)(p + 98304), d1 = *(const f32x4*)(p + 98308);
  bf16x8 r;
  r[0]=f2bf(a0[0]+b0[0]+c0[0]+d0[0]); r[1]=f2bf(a0[1]+b0[1]+c0[1]+d0[1]);
  r[2]=f2bf(a0[2]+b0[2]+c0[2]+d0[2]); r[3]=f2bf(a0[3]+b0[3]+c0[3]+d0[3]);
  r[4]=f2bf(a1[0]+b1[0]+c1[0]+d1[0]); r[5]=f2bf(a1[1]+b1[1]+c1[1]+d1[1]);
  r[6]=f2bf(a1[2]+b1[2]+c1[2]+d1[2]); r[7]=f2bf(a1[3]+b1[3]+c1[3]+d1[3]);
  return r;
}

// ---------------------------------------------------------------------------
// One cooperative kernel, 256 blocks x 256 threads (1024 waves), 8 phases.
// ---------------------------------------------------------------------------
__global__ __launch_bounds__(256) void k_mega(
    const int* __restrict__ wi, const float* __restrict__ lh,
    const float* __restrict__ th, const float* __restrict__ tree,
    const float* __restrict__ seq, const int* __restrict__ nnp,
    const float* __restrict__ emb, const float* __restrict__ Wih,
    const float* __restrict__ Whh, const float* __restrict__ bih,
    const float* __restrict__ bhh, const float* __restrict__ Wcomb,
    const float* __restrict__ bcomb, const float* __restrict__ Wout,
    float* __restrict__ out, float* __restrict__ ws)
{
  cg::grid_group grid = cg::this_grid();
  const int lane = threadIdx.x & 63;
  const int widx = threadIdx.x >> 6;
  const int gw   = blockIdx.x * 4 + widx;   // 0..1023
  const int al   = lane & 15, ah = lane >> 4;

  // workspace layout (floats)
  float* pgates = ws;                        // [8][3072][32] = 786432
  float* pcomb  = ws + 786432;               // [8][1024][32] = 262144
  float* pctx   = ws + 1048576;              // [4][32][1024] = 131072
  float* cur    = ws + 1179648;              // [32][1024]    = 32768
  float* scores = ws + 1212416;              // [32][255] pad 8192
  unsigned short* thb = (unsigned short*)(ws + 1220608);  // [32][1024] bf16
  float* vt2    = ws + 1236992;              // [2][32000][32] = 2048000

  float* o_prob = out;                       // (B,V)
  float* o_cur  = out + 1024000;             // (B,H)
  float* o_th   = out + 1056768;             // (B,H)
  float* o_ctx  = out + 1089536;             // (B,H)

  __shared__ float sw[4][64];

  // ---- Phase 1: gate partials.  tasks = 192 tiles x 8 k-splits -------------
  // compact gate rows {i:0..1023, g:1024..2047, o:2048..3071}; f skipped (c0=0)
  for (int task = gw; task < 1536; task += 1024) {
    int tile = task >> 3, ks = task & 7;
    int cgi = tile * 16 + al;
    int g = (cgi < 1024) ? cgi : cgi + 1024;
    const float* W = (ks < 4) ? Wih : Whh;
    int kbase = (ks & 3) * 256;
    const float* Arow = W + (size_t)g * HH + kbase + ah * 8;
    f32x4 acc_lo = {0.f,0.f,0.f,0.f}, acc_hi = {0.f,0.f,0.f,0.f};
    if (ks < 4) {
      const float* e_lo = emb + (size_t)wi[al] * HH + kbase + ah * 8;
      const float* e_hi = emb + (size_t)wi[al + 16] * HH + kbase + ah * 8;
      #pragma unroll
      for (int kk = 0; kk < 8; ++kk) {
        bf16x8 a = load_cvt8(Arow + kk * 32);
        acc_lo = MFMA(a, load_cvt8(e_lo + kk * 32), acc_lo);
        acc_hi = MFMA(a, load_cvt8(e_hi + kk * 32), acc_hi);
      }
    } else {
      const float* p_lo = lh + al * HH + kbase + ah * 8;
      const float* q_lo = th + al * HH + kbase + ah * 8;
      const float* p_hi = lh + (al + 16) * HH + kbase + ah * 8;
      const float* q_hi = th + (al + 16) * HH + kbase + ah * 8;
      #pragma unroll
      for (int kk = 0; kk < 8; ++kk) {
        bf16x8 a = load_cvt8(Arow + kk * 32);
        acc_lo = MFMA(a, load_add_cvt8(p_lo + kk * 32, q_lo + kk * 32), acc_lo);
        acc_hi = MFMA(a, load_add_cvt8(p_hi + kk * 32, q_hi + kk * 32), acc_hi);
      }
    }
    float* op = pgates + ((size_t)ks * 3072 + tile * 16) * 32;
    #pragma unroll
    for (int j = 0; j < 4; ++j) {
      int r = ah * 4 + j;
      op[r * 32 + al]      = acc_lo[j];
      op[r * 32 + al + 16] = acc_hi[j];
    }
  }
  grid.sync();

  // ---- Phase 2: LSTM cell -> cur -------------------------------------------
  if (gw < 512) {
    int idx = gw * 64 + lane;
    int b = idx & 31, h = idx >> 5;
    float iv = 0.f, gv = 0.f, ov = 0.f;
    #pragma unroll
    for (int ks = 0; ks < 8; ++ks) {
      const float* p = pgates + (size_t)ks * 3072 * 32;
      iv += p[(size_t)h * 32 + b];
      gv += p[(size_t)(1024 + h) * 32 + b];
      ov += p[(size_t)(2048 + h) * 32 + b];
    }
    iv += bih[h] + bhh[h];
    gv += bih[2048 + h] + bhh[2048 + h];
    ov += bih[3072 + h] + bhh[3072 + h];
    float ig = 1.f / (1.f + __expf(-iv));
    float og = 1.f / (1.f + __expf(-ov));
    float c1 = ig * tanhf(gv);
    float h1 = og * tanhf(c1);
    int s = 0;
    #pragma unroll
    for (int i = 0; i < BB; ++i) s += wi[i];
    float c = (s == 0) ? lh[b * HH + h] : h1;
    cur[b * HH + h] = c;
    o_cur[b * HH + h] = c;
  }
  grid.sync();

  // ---- Phase 3: attention scores (wave per (b,t)) --------------------------
  for (int task = gw; task < BB * NT; task += 1024) {
    int b = task & 31, t = task >> 5;
    int nn = nnp[b];
    int tl    = (t < LL) ? t : (t - LL);
    int limit = (t < LL) ? (nn + 1) : nn;
    if (tl >= limit) { if (lane == 0) scores[b * NT + t] = -1e30f; continue; }
    const float* row = (t < LL) ? (seq + ((size_t)t * BB + b) * HH)
                                : (tree + ((size_t)(t - LL) * BB + b) * HH);
    const float* c = cur + b * HH;
    float acc = 0.f;
    #pragma unroll
    for (int ch = 0; ch < 4; ++ch) {
      int k = ch * 256 + lane * 4;
      f32x4 e = *(const f32x4*)(row + k);
      f32x4 q = *(const f32x4*)(c + k);
      acc += e[0]*q[0] + e[1]*q[1] + e[2]*q[2] + e[3]*q[3];
    }
    #pragma unroll
    for (int off = 32; off; off >>= 1) acc += __shfl_xor(acc, off);
    if (lane == 0) scores[b * NT + t] = acc;
  }
  grid.sync();

  // ---- Phase 4: context partials. tasks = b(32) x hc(16) x tc(4) = 2048 ----
  // masked weights are exactly 0 -> uniform dense sum, no numNode dependence
  for (int task = gw; task < 2048; task += 1024) {   // exactly 2 iters/wave
    int b = task >> 6, rem = task & 63, hc = rem >> 2, tc = rem & 3;
    const float* sb = scores + b * NT;
    float s0 = sb[lane];
    float s1 = sb[64 + lane];
    float s2 = sb[128 + lane];
    float s3 = (lane < 63) ? sb[192 + lane] : -1e30f;
    float m = fmaxf(fmaxf(s0, s1), fmaxf(s2, s3));
    #pragma unroll
    for (int off = 32; off; off >>= 1) m = fmaxf(m, __shfl_xor(m, off));
    float z = __expf(s0 - m) + __expf(s1 - m) + __expf(s2 - m)
            + ((lane < 63) ? __expf(s3 - m) : 0.f);
    #pragma unroll
    for (int off = 32; off; off >>= 1) z += __shfl_xor(z, off);
    int t = tc * 64 + lane;
    float sown = (t < NT) ? sb[t] : -1e30f;
    sw[widx][lane] = __expf(sown - m) / z;
    __syncthreads();
    int h = hc * 64 + lane;
    int ntt = (tc == 3) ? 63 : 64;
    const float* base = (tc < 2)
        ? seq + ((size_t)(tc * 64) * BB + b) * HH + h
        : tree + ((size_t)(tc * 64 - LL) * BB + b) * HH + h;
    float acc = 0.f;
    #pragma unroll 8
    for (int tt = 0; tt < ntt; ++tt)
      acc += sw[widx][tt] * base[(size_t)tt * (BB * HH)];
    pctx[((size_t)tc * BB + b) * HH + h] = acc;
    __syncthreads();
  }
  grid.sync();

  // ---- Phase 5: comb partials. tasks = 64 tiles x 8 k-splits = 512 ---------
  if (gw < 512) {
    int tile = gw >> 3, ks = gw & 7;
    int mm = tile * 16 + al;
    int kbase = (ks & 3) * 256;
    const float* Arow = Wcomb + (size_t)mm * 2048 + ks * 256 + ah * 8;
    f32x4 acc_lo = {0.f,0.f,0.f,0.f}, acc_hi = {0.f,0.f,0.f,0.f};
    if (ks < 4) {
      const float* xlo = cur + al * HH + kbase + ah * 8;
      const float* xhi = cur + (al + 16) * HH + kbase + ah * 8;
      #pragma unroll
      for (int kk = 0; kk < 8; ++kk) {
        bf16x8 a = load_cvt8(Arow + kk * 32);
        acc_lo = MFMA(a, load_cvt8(xlo + kk * 32), acc_lo);
        acc_hi = MFMA(a, load_cvt8(xhi + kk * 32), acc_hi);
      }
    } else {
      int xc = kbase + ah * 8;
      #pragma unroll
      for (int kk = 0; kk < 8; ++kk) {
        bf16x8 a = load_cvt8(Arow + kk * 32);
        acc_lo = MFMA(a, sum4_cvt8(pctx, al,      xc + kk * 32), acc_lo);
        acc_hi = MFMA(a, sum4_cvt8(pctx, al + 16, xc + kk * 32), acc_hi);
      }
    }
    float* op = pcomb + ((size_t)ks * 1024 + tile * 16) * 32;
    #pragma unroll
    for (int j = 0; j < 4; ++j) {
      int r = ah * 4 + j;
      op[r * 32 + al]      = acc_lo[j];
      op[r * 32 + al + 16] = acc_hi[j];
    }
  }
  grid.sync();

  // ---- Phase 6: comb reduce + tanh -> o_th/thb ; ctx reduce -> o_ctx -------
  if (gw < 512) {
    int idx = gw * 64 + lane;
    int b = idx & 31, mm = idx >> 5;
    float v = 0.f;
    #pragma unroll
    for (int ks = 0; ks < 8; ++ks) v += pcomb[((size_t)ks * 1024 + mm) * 32 + b];
    v = tanhf(v + bcomb[mm]);
    o_th[b * HH + mm] = v;
    thb[b * HH + mm] = (unsigned short)f2bf(v);
    size_t ci = (size_t)b * HH + mm;
    o_ctx[ci] = pctx[ci] + pctx[32768 + ci] + pctx[65536 + ci] + pctx[98304 + ci];
  }
  grid.sync();

  // ---- Phase 7: W_out GEMV. tasks = 2000 tiles x 2 k-halves = 4000 ---------
  for (int task = gw; task < 4000; task += 1024) {
    int tile = task >> 1, half = task & 1;
    size_t row = (size_t)tile * 16 + al;
    const float* Arow = Wout + row * HH + half * 512 + ah * 8;
    const unsigned short* blo = thb + al * HH + half * 512 + ah * 8;
    const unsigned short* bhi = thb + (al + 16) * HH + half * 512 + ah * 8;
    f32x4 acc_lo = {0.f,0.f,0.f,0.f}, acc_hi = {0.f,0.f,0.f,0.f};
    #pragma unroll 4
    for (int kk = 0; kk < 16; ++kk) {
      bf16x8 a  = load_cvt8(Arow + kk * 32);
      bf16x8 bl = *(const bf16x8*)(blo + kk * 32);
      bf16x8 bh = *(const bf16x8*)(bhi + kk * 32);
      acc_lo = MFMA(a, bl, acc_lo);
      acc_hi = MFMA(a, bh, acc_hi);
    }
    float* op = vt2 + (size_t)half * 1024000 + (size_t)tile * 16 * 32;
    #pragma unroll
    for (int j = 0; j < 4; ++j) {
      int r = ah * 4 + j;
      op[r * 32 + al]      = acc_lo[j];
      op[r * 32 + al + 16] = acc_hi[j];
    }
  }
  grid.sync();

  // ---- Phase 8: softmax over batch (axis 0) --------------------------------
  if (gw < 500) {
    int v = gw * 64 + lane;
    const float* r0 = vt2 + (size_t)v * 32;
    const float* r1 = vt2 + 1024000 + (size_t)v * 32;
    float x[32];
    #pragma unroll
    for (int i = 0; i < 8; ++i) {
      f32x4 t0 = *(const f32x4*)(r0 + i * 4);
      f32x4 t1 = *(const f32x4*)(r1 + i * 4);
      x[i*4+0] = t0[0]+t1[0]; x[i*4+1] = t0[1]+t1[1];
      x[i*4+2] = t0[2]+t1[2]; x[i*4+3] = t0[3]+t1[3];
    }
    float m = x[0];
    #pragma unroll
    for (int i = 1; i < 32; ++i) m = fmaxf(m, x[i]);
    float z = 0.f;
    #pragma unroll
    for (int i = 0; i < 32; ++i) { x[i] = __expf(x[i] - m); z += x[i]; }
    float inv = 1.f / z;
    #pragma unroll
    for (int i = 0; i < 32; ++i) o_prob[(size_t)i * VV + v] = x[i] * inv;
  }
}

// ---------------------------------------------------------------------------
extern "C" void kernel_launch(void* const* d_in, const int* in_sizes, int n_in,
                              void* d_out, int out_size, void* d_ws, size_t ws_size,
                              hipStream_t stream) {
  const int*   wi    = (const int*)d_in[0];
  const float* lh    = (const float*)d_in[1];
  const float* thid  = (const float*)d_in[2];
  const float* tree  = (const float*)d_in[3];
  const float* seq   = (const float*)d_in[4];
  const int*   nnp   = (const int*)d_in[5];
  const float* emb   = (const float*)d_in[6];
  const float* Wih   = (const float*)d_in[7];
  const float* Whh   = (const float*)d_in[8];
  const float* bih   = (const float*)d_in[9];
  const float* bhh   = (const float*)d_in[10];
  const float* Wcomb = (const float*)d_in[11];
  const float* bcomb = (const float*)d_in[12];
  const float* Wout  = (const float*)d_in[13];
  // d_in[14] = b_out: unused — constant per v cancels in softmax over batch axis

  float* outp = (float*)d_out;
  float* wsp  = (float*)d_ws;

  void* args[] = {
    (void*)&wi, (void*)&lh, (void*)&thid, (void*)&tree, (void*)&seq,
    (void*)&nnp, (void*)&emb, (void*)&Wih, (void*)&Whh, (void*)&bih,
    (void*)&bhh, (void*)&Wcomb, (void*)&bcomb, (void*)&Wout,
    (void*)&outp, (void*)&wsp
  };
  hipLaunchCooperativeKernel((void*)k_mega, dim3(256), dim3(256), args, 0, stream);
}

// Round 7
// 360.386 us; speedup vs baseline: 1.7341x; 1.7341x over previous
//
#include <hip/hip_runtime.h>

#define BB 32
#define HH 1024
#define LL 128
#define TT 127
#define VV 32000
#define NT 255  // LL+TT

typedef __attribute__((ext_vector_type(8))) short bf16x8;
typedef __attribute__((ext_vector_type(4))) float f32x4;

#define MFMA(a, b, c) __builtin_amdgcn_mfma_f32_16x16x32_bf16((a), (b), (c), 0, 0, 0)

static __device__ __forceinline__ short f2bf(float f) {
  unsigned u = __builtin_bit_cast(unsigned, f);
  u += 0x7fffu + ((u >> 16) & 1u);   // round-to-nearest-even
  return (short)(u >> 16);
}

static __device__ __forceinline__ bf16x8 load_cvt8(const float* __restrict__ p) {
  f32x4 a = *(const f32x4*)p;
  f32x4 b = *(const f32x4*)(p + 4);
  bf16x8 r;
  r[0]=f2bf(a[0]); r[1]=f2bf(a[1]); r[2]=f2bf(a[2]); r[3]=f2bf(a[3]);
  r[4]=f2bf(b[0]); r[5]=f2bf(b[1]); r[6]=f2bf(b[2]); r[7]=f2bf(b[3]);
  return r;
}

static __device__ __forceinline__ bf16x8 load_add_cvt8(const float* __restrict__ p,
                                                       const float* __restrict__ q) {
  f32x4 a = *(const f32x4*)p, a2 = *(const f32x4*)(p + 4);
  f32x4 b = *(const f32x4*)q, b2 = *(const f32x4*)(q + 4);
  bf16x8 r;
  r[0]=f2bf(a[0]+b[0]); r[1]=f2bf(a[1]+b[1]); r[2]=f2bf(a[2]+b[2]); r[3]=f2bf(a[3]+b[3]);
  r[4]=f2bf(a2[0]+b2[0]); r[5]=f2bf(a2[1]+b2[1]); r[6]=f2bf(a2[2]+b2[2]); r[7]=f2bf(a2[3]+b2[3]);
  return r;
}

// ---------------------------------------------------------------------------
// 1) gates partials: compact rows {i, g, o} (f skipped: c0 == 0).
//    768 blocks x 64 thr: 192 tiles x 4 k-splits. pgates[ks][3072][32]
// ---------------------------------------------------------------------------
__global__ __launch_bounds__(64) void k_gates(
    const int* __restrict__ wi, const float* __restrict__ lh,
    const float* __restrict__ th, const float* __restrict__ emb,
    const float* __restrict__ W_ih, const float* __restrict__ W_hh,
    float* __restrict__ pgates)
{
  int lane = threadIdx.x;
  int tile = blockIdx.x >> 2;     // 0..191
  int ks   = blockIdx.x & 3;
  int al = lane & 15, ah = lane >> 4;
  int cg = tile * 16 + al;
  int g  = (cg < 1024) ? cg : cg + 1024;
  const float* W = (ks < 2) ? W_ih : W_hh;
  int kbase = (ks & 1) * 512;
  const float* Arow = W + (size_t)g * HH + kbase + ah * 8;
  f32x4 acc_lo = {0.f,0.f,0.f,0.f}, acc_hi = {0.f,0.f,0.f,0.f};

  if (ks < 2) {
    const float* e_lo = emb + (size_t)wi[al] * HH + kbase + ah * 8;
    const float* e_hi = emb + (size_t)wi[al + 16] * HH + kbase + ah * 8;
    #pragma unroll 4
    for (int kk = 0; kk < 16; ++kk) {
      bf16x8 a = load_cvt8(Arow + kk * 32);
      acc_lo = MFMA(a, load_cvt8(e_lo + kk * 32), acc_lo);
      acc_hi = MFMA(a, load_cvt8(e_hi + kk * 32), acc_hi);
    }
  } else {
    const float* p_lo = lh + al * HH + kbase + ah * 8;
    const float* q_lo = th + al * HH + kbase + ah * 8;
    const float* p_hi = lh + (al + 16) * HH + kbase + ah * 8;
    const float* q_hi = th + (al + 16) * HH + kbase + ah * 8;
    #pragma unroll 4
    for (int kk = 0; kk < 16; ++kk) {
      bf16x8 a = load_cvt8(Arow + kk * 32);
      acc_lo = MFMA(a, load_add_cvt8(p_lo + kk * 32, q_lo + kk * 32), acc_lo);
      acc_hi = MFMA(a, load_add_cvt8(p_hi + kk * 32, q_hi + kk * 32), acc_hi);
    }
  }
  float* outp = pgates + ((size_t)ks * 3072 + tile * 16) * 32;
  #pragma unroll
  for (int j = 0; j < 4; ++j) {
    int row = ah * 4 + j;
    outp[row * 32 + al]      = acc_lo[j];
    outp[row * 32 + al + 16] = acc_hi[j];
  }
}

// ---------------------------------------------------------------------------
// 2) LSTM cell: reduce partials, biases, nonlinearities, begin-select -> cur
// ---------------------------------------------------------------------------
__global__ __launch_bounds__(256) void k_cell(
    const float* __restrict__ pgates, const float* __restrict__ b_ih,
    const float* __restrict__ b_hh, const int* __restrict__ wi,
    const float* __restrict__ lh, float* __restrict__ cur_ws,
    float* __restrict__ out_cur)
{
  __shared__ int s_begin;
  if (threadIdx.x == 0) {
    int s = 0;
    #pragma unroll
    for (int i = 0; i < BB; ++i) s += wi[i];
    s_begin = (s == 0);
  }
  __syncthreads();
  int b = threadIdx.x & 31;
  int h = blockIdx.x * 8 + (threadIdx.x >> 5);
  float iv = 0.f, gv = 0.f, ov = 0.f;
  #pragma unroll
  for (int ks = 0; ks < 4; ++ks) {
    const float* p = pgates + (size_t)ks * 3072 * 32;
    iv += p[(size_t)h * 32 + b];
    gv += p[(size_t)(1024 + h) * 32 + b];
    ov += p[(size_t)(2048 + h) * 32 + b];
  }
  iv += b_ih[h] + b_hh[h];
  gv += b_ih[2048 + h] + b_hh[2048 + h];
  ov += b_ih[3072 + h] + b_hh[3072 + h];
  float ig = 1.f / (1.f + __expf(-iv));
  float og = 1.f / (1.f + __expf(-ov));
  float c1 = ig * tanhf(gv);
  float h1 = og * tanhf(c1);
  float c  = s_begin ? lh[b * HH + h] : h1;
  cur_ws[b * HH + h] = c;
  out_cur[b * HH + h] = c;
}

// ---------------------------------------------------------------------------
// 3) attention scores: one wave per (b, t); masked positions write -1e30
// ---------------------------------------------------------------------------
__global__ __launch_bounds__(256) void k_scores(
    const float* __restrict__ cur, const float* __restrict__ seq,
    const float* __restrict__ tree, const int* __restrict__ numNode,
    float* __restrict__ scores)
{
  int lane = threadIdx.x & 63;
  int gw = blockIdx.x * 4 + (threadIdx.x >> 6);
  if (gw >= BB * NT) return;
  int b = gw & 31, t = gw >> 5;
  int nn = numNode[b];
  int tl    = (t < LL) ? t : (t - LL);
  int limit = (t < LL) ? (nn + 1) : nn;
  if (tl >= limit) { if (lane == 0) scores[b * NT + t] = -1e30f; return; }
  const float* row = (t < LL) ? (seq + ((size_t)t * BB + b) * HH)
                              : (tree + ((size_t)(t - LL) * BB + b) * HH);
  const float* c = cur + b * HH;
  float acc = 0.f;
  #pragma unroll
  for (int ch = 0; ch < 4; ++ch) {
    int k = ch * 256 + lane * 4;
    f32x4 e = *(const f32x4*)(row + k);
    f32x4 q = *(const f32x4*)(c + k);
    acc += e[0]*q[0] + e[1]*q[1] + e[2]*q[2] + e[3]*q[3];
  }
  #pragma unroll
  for (int off = 32; off; off >>= 1) acc += __shfl_xor(acc, off);
  if (lane == 0) scores[b * NT + t] = acc;
}

// ---------------------------------------------------------------------------
// 4) context: 512 blocks (b x hc16) x 256 thr (h64 x tc4).
//    In-block softmax over 255 (masked weights are exactly 0 -> dense sum).
// ---------------------------------------------------------------------------
__global__ __launch_bounds__(256) void k_context(
    const float* __restrict__ scores, const float* __restrict__ seq,
    const float* __restrict__ tree, float* __restrict__ ctx_ws,
    float* __restrict__ out_ctx)
{
  int b  = blockIdx.x >> 4;
  int hc = blockIdx.x & 15;
  int tid = threadIdx.x;
  int lane = tid & 63, wv = tid >> 6;
  __shared__ float w[256];
  __shared__ float red[8];
  __shared__ float part[4][64];

  float s = (tid < NT) ? scores[b * NT + tid] : -1e30f;
  float m = s;
  #pragma unroll
  for (int off = 32; off; off >>= 1) m = fmaxf(m, __shfl_xor(m, off));
  if (lane == 0) red[wv] = m;
  __syncthreads();
  m = fmaxf(fmaxf(red[0], red[1]), fmaxf(red[2], red[3]));
  float e = (tid < NT) ? __expf(s - m) : 0.f;
  float z = e;
  #pragma unroll
  for (int off = 32; off; off >>= 1) z += __shfl_xor(z, off);
  if (lane == 0) red[4 + wv] = z;
  __syncthreads();
  z = red[4] + red[5] + red[6] + red[7];
  w[tid] = e / z;
  __syncthreads();

  int h  = hc * 64 + lane;
  int tc = wv;                         // 0..3, uniform per wave
  int ntt = (tc == 3) ? 63 : 64;
  const float* base = (tc < 2)
      ? seq + ((size_t)(tc * 64) * BB + b) * HH + h
      : tree + ((size_t)(tc * 64 - LL) * BB + b) * HH + h;
  const float* wp = &w[tc * 64];
  float acc = 0.f;
  #pragma unroll 8
  for (int tt = 0; tt < ntt; ++tt)
    acc += wp[tt] * base[(size_t)tt * (BB * HH)];
  part[tc][lane] = acc;
  __syncthreads();
  if (tc == 0) {
    float v = part[0][lane] + part[1][lane] + part[2][lane] + part[3][lane];
    ctx_ws[b * HH + h] = v;
    out_ctx[b * HH + h] = v;
  }
}

// ---------------------------------------------------------------------------
// 5) comb partials: M=1024, K=2048 ([cur | ctx]), K-split 4 -> pcomb[4][1024][32]
// ---------------------------------------------------------------------------
__global__ __launch_bounds__(64) void k_comb(
    const float* __restrict__ W_comb, const float* __restrict__ cur,
    const float* __restrict__ ctx, float* __restrict__ pcomb)
{
  int lane = threadIdx.x;
  int tile = blockIdx.x >> 2;   // 0..63
  int ks   = blockIdx.x & 3;
  int al = lane & 15, ah = lane >> 4;
  int m = tile * 16 + al;
  int kbase = ks * 512;
  const float* Arow = W_comb + (size_t)m * 2048 + kbase + ah * 8;
  const float* X = (ks < 2) ? cur : ctx;
  int xkb = kbase & 1023;
  const float* xlo = X + al * HH + xkb + ah * 8;
  const float* xhi = X + (al + 16) * HH + xkb + ah * 8;
  f32x4 acc_lo = {0.f,0.f,0.f,0.f}, acc_hi = {0.f,0.f,0.f,0.f};
  #pragma unroll 4
  for (int kk = 0; kk < 16; ++kk) {
    bf16x8 a = load_cvt8(Arow + kk * 32);
    acc_lo = MFMA(a, load_cvt8(xlo + kk * 32), acc_lo);
    acc_hi = MFMA(a, load_cvt8(xhi + kk * 32), acc_hi);
  }
  float* outp = pcomb + ((size_t)ks * 1024 + tile * 16) * 32;
  #pragma unroll
  for (int j = 0; j < 4; ++j) {
    int row = ah * 4 + j;
    outp[row * 32 + al]      = acc_lo[j];
    outp[row * 32 + al + 16] = acc_hi[j];
  }
}

// ---------------------------------------------------------------------------
// 6) comb reduce + bias + tanh -> tanh_h (f32 out) + bf16 copy for W_out GEMM
// ---------------------------------------------------------------------------
__global__ __launch_bounds__(256) void k_combred(
    const float* __restrict__ pcomb, const float* __restrict__ b_comb,
    float* __restrict__ out_th, unsigned short* __restrict__ thb)
{
  int b = threadIdx.x & 31;
  int m = blockIdx.x * 8 + (threadIdx.x >> 5);
  float v = 0.f;
  #pragma unroll
  for (int ks = 0; ks < 4; ++ks) v += pcomb[((size_t)ks * 1024 + m) * 32 + b];
  v = tanhf(v + b_comb[m]);
  out_th[b * HH + m] = v;
  thb[b * HH + m] = (unsigned short)f2bf(v);
}

// ---------------------------------------------------------------------------
// 7) out_vec = tanh_h @ W_out.T  (bias cancels in axis-0 softmax).
//    500 blocks x 4 waves; each wave 16 vocab rows, full K. vt[v][b].
// ---------------------------------------------------------------------------
__global__ __launch_bounds__(256) void k_wout(
    const float* __restrict__ W_out, const unsigned short* __restrict__ thb,
    float* __restrict__ vt)
{
  int lane = threadIdx.x & 63;
  int tile = blockIdx.x * 4 + (threadIdx.x >> 6);   // 0..1999
  int al = lane & 15, ah = lane >> 4;
  size_t row = (size_t)tile * 16 + al;
  const float* Arow = W_out + row * HH + ah * 8;
  const unsigned short* blo = thb + al * HH + ah * 8;
  const unsigned short* bhi = thb + (al + 16) * HH + ah * 8;
  f32x4 acc_lo = {0.f,0.f,0.f,0.f}, acc_hi = {0.f,0.f,0.f,0.f};
  #pragma unroll 4
  for (int kk = 0; kk < 32; ++kk) {
    bf16x8 a  = load_cvt8(Arow + kk * 32);
    bf16x8 bl = *(const bf16x8*)(blo + kk * 32);
    bf16x8 bh = *(const bf16x8*)(bhi + kk * 32);
    acc_lo = MFMA(a, bl, acc_lo);
    acc_hi = MFMA(a, bh, acc_hi);
  }
  float* outp = vt + (size_t)tile * 16 * 32;
  #pragma unroll
  for (int j = 0; j < 4; ++j) {
    int r = ah * 4 + j;
    outp[r * 32 + al]      = acc_lo[j];
    outp[r * 32 + al + 16] = acc_hi[j];
  }
}

// ---------------------------------------------------------------------------
// 8) softmax over batch (axis 0): thread per vocab entry
// ---------------------------------------------------------------------------
__global__ __launch_bounds__(256) void k_psoftmax(
    const float* __restrict__ vt, float* __restrict__ prob)
{
  int v = blockIdx.x * 256 + threadIdx.x;
  const float* r = vt + (size_t)v * 32;
  float x[32];
  #pragma unroll
  for (int i = 0; i < 8; ++i) {
    f32x4 t = *(const f32x4*)(r + i * 4);
    x[i*4+0] = t[0]; x[i*4+1] = t[1]; x[i*4+2] = t[2]; x[i*4+3] = t[3];
  }
  float m = x[0];
  #pragma unroll
  for (int i = 1; i < 32; ++i) m = fmaxf(m, x[i]);
  float z = 0.f;
  #pragma unroll
  for (int i = 0; i < 32; ++i) { x[i] = __expf(x[i] - m); z += x[i]; }
  float inv = 1.f / z;
  #pragma unroll
  for (int i = 0; i < 32; ++i) prob[(size_t)i * VV + v] = x[i] * inv;
}

// ---------------------------------------------------------------------------
extern "C" void kernel_launch(void* const* d_in, const int* in_sizes, int n_in,
                              void* d_out, int out_size, void* d_ws, size_t ws_size,
                              hipStream_t stream) {
  const int*   wi    = (const int*)d_in[0];
  const float* lh    = (const float*)d_in[1];
  const float* thid  = (const float*)d_in[2];
  const float* tree  = (const float*)d_in[3];
  const float* seq   = (const float*)d_in[4];
  const int*   nn    = (const int*)d_in[5];
  const float* emb   = (const float*)d_in[6];
  const float* Wih   = (const float*)d_in[7];
  const float* Whh   = (const float*)d_in[8];
  const float* bih   = (const float*)d_in[9];
  const float* bhh   = (const float*)d_in[10];
  const float* Wcomb = (const float*)d_in[11];
  const float* bcomb = (const float*)d_in[12];
  const float* Wout  = (const float*)d_in[13];
  // d_in[14] = b_out: unused — per-v constant cancels in softmax over batch axis

  float* out = (float*)d_out;
  float* ws  = (float*)d_ws;
  float* pgates = ws;                       // 4*3072*32 = 393216
  float* pcomb  = ws + 393216;              // 4*1024*32 = 131072
  float* cur    = ws + 524288;              // 32768
  float* ctx    = ws + 557056;              // 32768
  float* scores = ws + 589824;              // 8160 (pad 8192)
  unsigned short* thb = (unsigned short*)(ws + 598016);  // 32768 bf16
  float* vt     = ws + 614400;              // 32000*32 = 1024000

  float* o_prob = out;                      // (B,V)
  float* o_cur  = out + 1024000;            // (B,H)
  float* o_th   = out + 1056768;            // (B,H)
  float* o_ctx  = out + 1089536;            // (B,H)

  k_gates   <<<dim3(768),  dim3(64),  0, stream>>>(wi, lh, thid, emb, Wih, Whh, pgates);
  k_cell    <<<dim3(128),  dim3(256), 0, stream>>>(pgates, bih, bhh, wi, lh, cur, o_cur);
  k_scores  <<<dim3(2040), dim3(256), 0, stream>>>(cur, seq, tree, nn, scores);
  k_context <<<dim3(512),  dim3(256), 0, stream>>>(scores, seq, tree, ctx, o_ctx);
  k_comb    <<<dim3(256),  dim3(64),  0, stream>>>(Wcomb, cur, ctx, pcomb);
  k_combred <<<dim3(128),  dim3(256), 0, stream>>>(pcomb, bcomb, o_th, thb);
  k_wout    <<<dim3(500),  dim3(256), 0, stream>>>(Wout, thb, vt);
  k_psoftmax<<<dim3(125),  dim3(256), 0, stream>>>(vt, o_prob);
}

// Round 8
// 355.813 us; speedup vs baseline: 1.7564x; 1.0129x over previous
//
#include <hip/hip_runtime.h>

#define BB 32
#define HH 1024
#define LL 128
#define TT 127
#define VV 32000
#define NT 255  // LL+TT

typedef __attribute__((ext_vector_type(8))) short bf16x8;
typedef __attribute__((ext_vector_type(4))) float f32x4;

#define MFMA(a, b, c) __builtin_amdgcn_mfma_f32_16x16x32_bf16((a), (b), (c), 0, 0, 0)

static __device__ __forceinline__ short f2bf(float f) {
  unsigned u = __builtin_bit_cast(unsigned, f);
  u += 0x7fffu + ((u >> 16) & 1u);   // round-to-nearest-even
  return (short)(u >> 16);
}

static __device__ __forceinline__ bf16x8 load_cvt8(const float* __restrict__ p) {
  f32x4 a = *(const f32x4*)p;
  f32x4 b = *(const f32x4*)(p + 4);
  bf16x8 r;
  r[0]=f2bf(a[0]); r[1]=f2bf(a[1]); r[2]=f2bf(a[2]); r[3]=f2bf(a[3]);
  r[4]=f2bf(b[0]); r[5]=f2bf(b[1]); r[6]=f2bf(b[2]); r[7]=f2bf(b[3]);
  return r;
}

static __device__ __forceinline__ bf16x8 load_add_cvt8(const float* __restrict__ p,
                                                       const float* __restrict__ q) {
  f32x4 a = *(const f32x4*)p, a2 = *(const f32x4*)(p + 4);
  f32x4 b = *(const f32x4*)q, b2 = *(const f32x4*)(q + 4);
  bf16x8 r;
  r[0]=f2bf(a[0]+b[0]); r[1]=f2bf(a[1]+b[1]); r[2]=f2bf(a[2]+b[2]); r[3]=f2bf(a[3]+b[3]);
  r[4]=f2bf(a2[0]+b2[0]); r[5]=f2bf(a2[1]+b2[1]); r[6]=f2bf(a2[2]+b2[2]); r[7]=f2bf(a2[3]+b2[3]);
  return r;
}

// ---------------------------------------------------------------------------
// 1) gates partials: compact rows {i, g, o} (f skipped: c0 == 0).
//    768 blocks x 64 thr: 192 tiles x 4 k-splits. pgates[ks][3072][32]
// ---------------------------------------------------------------------------
__global__ __launch_bounds__(64) void k_gates(
    const int* __restrict__ wi, const float* __restrict__ lh,
    const float* __restrict__ th, const float* __restrict__ emb,
    const float* __restrict__ W_ih, const float* __restrict__ W_hh,
    float* __restrict__ pgates)
{
  int lane = threadIdx.x;
  int tile = blockIdx.x >> 2;     // 0..191
  int ks   = blockIdx.x & 3;
  int al = lane & 15, ah = lane >> 4;
  int cg = tile * 16 + al;
  int g  = (cg < 1024) ? cg : cg + 1024;
  const float* W = (ks < 2) ? W_ih : W_hh;
  int kbase = (ks & 1) * 512;
  const float* Arow = W + (size_t)g * HH + kbase + ah * 8;
  f32x4 acc_lo = {0.f,0.f,0.f,0.f}, acc_hi = {0.f,0.f,0.f,0.f};

  if (ks < 2) {
    const float* e_lo = emb + (size_t)wi[al] * HH + kbase + ah * 8;
    const float* e_hi = emb + (size_t)wi[al + 16] * HH + kbase + ah * 8;
    #pragma unroll 4
    for (int kk = 0; kk < 16; ++kk) {
      bf16x8 a = load_cvt8(Arow + kk * 32);
      acc_lo = MFMA(a, load_cvt8(e_lo + kk * 32), acc_lo);
      acc_hi = MFMA(a, load_cvt8(e_hi + kk * 32), acc_hi);
    }
  } else {
    const float* p_lo = lh + al * HH + kbase + ah * 8;
    const float* q_lo = th + al * HH + kbase + ah * 8;
    const float* p_hi = lh + (al + 16) * HH + kbase + ah * 8;
    const float* q_hi = th + (al + 16) * HH + kbase + ah * 8;
    #pragma unroll 4
    for (int kk = 0; kk < 16; ++kk) {
      bf16x8 a = load_cvt8(Arow + kk * 32);
      acc_lo = MFMA(a, load_add_cvt8(p_lo + kk * 32, q_lo + kk * 32), acc_lo);
      acc_hi = MFMA(a, load_add_cvt8(p_hi + kk * 32, q_hi + kk * 32), acc_hi);
    }
  }
  float* outp = pgates + ((size_t)ks * 3072 + tile * 16) * 32;
  #pragma unroll
  for (int j = 0; j < 4; ++j) {
    int row = ah * 4 + j;
    outp[row * 32 + al]      = acc_lo[j];
    outp[row * 32 + al + 16] = acc_hi[j];
  }
}

// ---------------------------------------------------------------------------
// 2) LSTM cell: reduce partials, biases, nonlinearities, begin-select -> cur
// ---------------------------------------------------------------------------
__global__ __launch_bounds__(256) void k_cell(
    const float* __restrict__ pgates, const float* __restrict__ b_ih,
    const float* __restrict__ b_hh, const int* __restrict__ wi,
    const float* __restrict__ lh, float* __restrict__ cur_ws,
    float* __restrict__ out_cur)
{
  __shared__ int s_begin;
  if (threadIdx.x == 0) {
    int s = 0;
    #pragma unroll
    for (int i = 0; i < BB; ++i) s += wi[i];
    s_begin = (s == 0);
  }
  __syncthreads();
  int b = threadIdx.x & 31;
  int h = blockIdx.x * 8 + (threadIdx.x >> 5);
  float iv = 0.f, gv = 0.f, ov = 0.f;
  #pragma unroll
  for (int ks = 0; ks < 4; ++ks) {
    const float* p = pgates + (size_t)ks * 3072 * 32;
    iv += p[(size_t)h * 32 + b];
    gv += p[(size_t)(1024 + h) * 32 + b];
    ov += p[(size_t)(2048 + h) * 32 + b];
  }
  iv += b_ih[h] + b_hh[h];
  gv += b_ih[2048 + h] + b_hh[2048 + h];
  ov += b_ih[3072 + h] + b_hh[3072 + h];
  float ig = 1.f / (1.f + __expf(-iv));
  float og = 1.f / (1.f + __expf(-ov));
  float c1 = ig * tanhf(gv);
  float h1 = og * tanhf(c1);
  float c  = s_begin ? lh[b * HH + h] : h1;
  cur_ws[b * HH + h] = c;
  out_cur[b * HH + h] = c;
}

// ---------------------------------------------------------------------------
// 3) attention scores: one wave per (b, t); masked positions write -1e30
// ---------------------------------------------------------------------------
__global__ __launch_bounds__(256) void k_scores(
    const float* __restrict__ cur, const float* __restrict__ seq,
    const float* __restrict__ tree, const int* __restrict__ numNode,
    float* __restrict__ scores)
{
  int lane = threadIdx.x & 63;
  int gw = blockIdx.x * 4 + (threadIdx.x >> 6);
  if (gw >= BB * NT) return;
  int b = gw & 31, t = gw >> 5;
  int nn = numNode[b];
  int tl    = (t < LL) ? t : (t - LL);
  int limit = (t < LL) ? (nn + 1) : nn;
  if (tl >= limit) { if (lane == 0) scores[b * NT + t] = -1e30f; return; }
  const float* row = (t < LL) ? (seq + ((size_t)t * BB + b) * HH)
                              : (tree + ((size_t)(t - LL) * BB + b) * HH);
  const float* c = cur + b * HH;
  float acc = 0.f;
  #pragma unroll
  for (int ch = 0; ch < 4; ++ch) {
    int k = ch * 256 + lane * 4;
    f32x4 e = *(const f32x4*)(row + k);
    f32x4 q = *(const f32x4*)(c + k);
    acc += e[0]*q[0] + e[1]*q[1] + e[2]*q[2] + e[3]*q[3];
  }
  #pragma unroll
  for (int off = 32; off; off >>= 1) acc += __shfl_xor(acc, off);
  if (lane == 0) scores[b * NT + t] = acc;
}

// ---------------------------------------------------------------------------
// 4) context: 512 blocks (b x hc16) x 256 thr (h64 x tc4).
//    In-block softmax over 255; per-wave t-loop capped at the valid count
//    (masked weights are exactly 0 -> skipping them is exact).
// ---------------------------------------------------------------------------
__global__ __launch_bounds__(256) void k_context(
    const float* __restrict__ scores, const float* __restrict__ seq,
    const float* __restrict__ tree, const int* __restrict__ numNode,
    float* __restrict__ ctx_ws, float* __restrict__ out_ctx)
{
  int b  = blockIdx.x >> 4;
  int hc = blockIdx.x & 15;
  int tid = threadIdx.x;
  int lane = tid & 63, wv = tid >> 6;
  __shared__ float w[256];
  __shared__ float red[8];
  __shared__ float part[4][64];

  float s = (tid < NT) ? scores[b * NT + tid] : -1e30f;
  float m = s;
  #pragma unroll
  for (int off = 32; off; off >>= 1) m = fmaxf(m, __shfl_xor(m, off));
  if (lane == 0) red[wv] = m;
  __syncthreads();
  m = fmaxf(fmaxf(red[0], red[1]), fmaxf(red[2], red[3]));
  float e = (tid < NT) ? __expf(s - m) : 0.f;
  float z = e;
  #pragma unroll
  for (int off = 32; off; off >>= 1) z += __shfl_xor(z, off);
  if (lane == 0) red[4 + wv] = z;
  __syncthreads();
  z = red[4] + red[5] + red[6] + red[7];
  w[tid] = e / z;
  __syncthreads();

  int h  = hc * 64 + lane;
  int tc = wv;                         // 0..3, uniform per wave
  int nn = numNode[b];
  int nl = nn + 1;
  int lim;
  if      (tc == 0) lim = (nl < 64) ? nl : 64;
  else if (tc == 1) { lim = nl - 64; lim = (lim < 0) ? 0 : ((lim > 64) ? 64 : lim); }
  else if (tc == 2) lim = (nn < 64) ? nn : 64;
  else              { lim = nn - 64; lim = (lim < 0) ? 0 : ((lim > 63) ? 63 : lim); }
  const float* base = (tc < 2)
      ? seq + ((size_t)(tc * 64) * BB + b) * HH + h
      : tree + ((size_t)(tc * 64 - LL) * BB + b) * HH + h;
  const float* wp = &w[tc * 64];
  float acc = 0.f;
  #pragma unroll 4
  for (int tt = 0; tt < lim; ++tt)
    acc += wp[tt] * base[(size_t)tt * (BB * HH)];
  part[tc][lane] = acc;
  __syncthreads();
  if (tc == 0) {
    float v = part[0][lane] + part[1][lane] + part[2][lane] + part[3][lane];
    ctx_ws[b * HH + h] = v;
    out_ctx[b * HH + h] = v;
  }
}

// ---------------------------------------------------------------------------
// 5) comb fused: 64 blocks x 4 waves (wave = k-split of 512 over [cur|ctx]),
//    LDS reduce across waves, + bias + tanh -> o_th (f32) + thb (bf16)
// ---------------------------------------------------------------------------
__global__ __launch_bounds__(256) void k_comb(
    const float* __restrict__ W_comb, const float* __restrict__ cur,
    const float* __restrict__ ctx, const float* __restrict__ b_comb,
    float* __restrict__ out_th, unsigned short* __restrict__ thb)
{
  int lane = threadIdx.x & 63;
  int wv   = threadIdx.x >> 6;        // k-split 0..3
  int tile = blockIdx.x;              // 0..63
  int al = lane & 15, ah = lane >> 4;
  int m = tile * 16 + al;
  int kbase = wv * 512;
  const float* Arow = W_comb + (size_t)m * 2048 + kbase + ah * 8;
  const float* X = (wv < 2) ? cur : ctx;
  int xkb = kbase & 1023;
  const float* xlo = X + al * HH + xkb + ah * 8;
  const float* xhi = X + (al + 16) * HH + xkb + ah * 8;
  f32x4 acc_lo = {0.f,0.f,0.f,0.f}, acc_hi = {0.f,0.f,0.f,0.f};
  #pragma unroll 4
  for (int kk = 0; kk < 16; ++kk) {
    bf16x8 a = load_cvt8(Arow + kk * 32);
    acc_lo = MFMA(a, load_cvt8(xlo + kk * 32), acc_lo);
    acc_hi = MFMA(a, load_cvt8(xhi + kk * 32), acc_hi);
  }
  __shared__ float red[4][16][32];
  #pragma unroll
  for (int j = 0; j < 4; ++j) {
    int r = ah * 4 + j;               // m-local row
    red[wv][r][al]      = acc_lo[j];
    red[wv][r][al + 16] = acc_hi[j];
  }
  __syncthreads();
  int tid = threadIdx.x;
  int ml = tid >> 4, b0 = (tid & 15) * 2;
  float v0 = red[0][ml][b0]   + red[1][ml][b0]   + red[2][ml][b0]   + red[3][ml][b0];
  float v1 = red[0][ml][b0+1] + red[1][ml][b0+1] + red[2][ml][b0+1] + red[3][ml][b0+1];
  int mg = tile * 16 + ml;
  float bc = b_comb[mg];
  float t0 = tanhf(v0 + bc), t1 = tanhf(v1 + bc);
  out_th[b0 * HH + mg]       = t0;
  out_th[(b0 + 1) * HH + mg] = t1;
  thb[b0 * HH + mg]       = (unsigned short)f2bf(t0);
  thb[(b0 + 1) * HH + mg] = (unsigned short)f2bf(t1);
}

// ---------------------------------------------------------------------------
// 6) W_out GEMV + batch-softmax fused. 500 blocks x 4 waves; wave = 16 vocab
//    rows, full K. Wave holds all 32 batch logits per v -> in-wave softmax
//    (shfl over the 16-lane al-group), LDS transpose, coalesced prob write.
//    b_out skipped: constant per v cancels in softmax over batch.
// ---------------------------------------------------------------------------
__global__ __launch_bounds__(256) void k_wout(
    const float* __restrict__ W_out, const unsigned short* __restrict__ thb,
    float* __restrict__ prob)
{
  int lane = threadIdx.x & 63;
  int wv   = threadIdx.x >> 6;
  int tile = blockIdx.x * 4 + wv;     // 0..1999
  int al = lane & 15, ah = lane >> 4;
  size_t row = (size_t)tile * 16 + al;
  const float* Arow = W_out + row * HH + ah * 8;
  const unsigned short* blo = thb + al * HH + ah * 8;
  const unsigned short* bhi = thb + (al + 16) * HH + ah * 8;
  f32x4 acc_lo = {0.f,0.f,0.f,0.f}, acc_hi = {0.f,0.f,0.f,0.f};
  #pragma unroll 4
  for (int kk = 0; kk < 32; ++kk) {
    bf16x8 a  = load_cvt8(Arow + kk * 32);
    bf16x8 bl = *(const bf16x8*)(blo + kk * 32);
    bf16x8 bh = *(const bf16x8*)(bhi + kk * 32);
    acc_lo = MFMA(a, bl, acc_lo);
    acc_hi = MFMA(a, bh, acc_hi);
  }
  // softmax over batch per v: D col (al) = batch, row (ah*4+j) = v-local
  __shared__ float sprob[32][65];
  #pragma unroll
  for (int j = 0; j < 4; ++j) {
    float m = fmaxf(acc_lo[j], acc_hi[j]);
    #pragma unroll
    for (int mk = 1; mk < 16; mk <<= 1) m = fmaxf(m, __shfl_xor(m, mk));
    float e0 = __expf(acc_lo[j] - m);
    float e1 = __expf(acc_hi[j] - m);
    float z = e0 + e1;
    #pragma unroll
    for (int mk = 1; mk < 16; mk <<= 1) z += __shfl_xor(z, mk);
    float inv = 1.f / z;
    int vl = wv * 16 + ah * 4 + j;    // v-local within block's 64
    sprob[al][vl]      = e0 * inv;
    sprob[al + 16][vl] = e1 * inv;
  }
  __syncthreads();
  int tid = threadIdx.x;
  int b = tid >> 3, vc = (tid & 7) * 8;
  size_t v0 = (size_t)blockIdx.x * 64 + vc;
  float* op = prob + (size_t)b * VV + v0;
  f32x4 w0 = { sprob[b][vc],   sprob[b][vc+1], sprob[b][vc+2], sprob[b][vc+3] };
  f32x4 w1 = { sprob[b][vc+4], sprob[b][vc+5], sprob[b][vc+6], sprob[b][vc+7] };
  *(f32x4*)op       = w0;
  *(f32x4*)(op + 4) = w1;
}

// ---------------------------------------------------------------------------
extern "C" void kernel_launch(void* const* d_in, const int* in_sizes, int n_in,
                              void* d_out, int out_size, void* d_ws, size_t ws_size,
                              hipStream_t stream) {
  const int*   wi    = (const int*)d_in[0];
  const float* lh    = (const float*)d_in[1];
  const float* thid  = (const float*)d_in[2];
  const float* tree  = (const float*)d_in[3];
  const float* seq   = (const float*)d_in[4];
  const int*   nn    = (const int*)d_in[5];
  const float* emb   = (const float*)d_in[6];
  const float* Wih   = (const float*)d_in[7];
  const float* Whh   = (const float*)d_in[8];
  const float* bih   = (const float*)d_in[9];
  const float* bhh   = (const float*)d_in[10];
  const float* Wcomb = (const float*)d_in[11];
  const float* bcomb = (const float*)d_in[12];
  const float* Wout  = (const float*)d_in[13];
  // d_in[14] = b_out: unused — per-v constant cancels in softmax over batch axis

  float* out = (float*)d_out;
  float* ws  = (float*)d_ws;
  float* pgates = ws;                       // 4*3072*32 = 393216
  float* cur    = ws + 393216;              // 32768
  float* ctx    = ws + 425984;              // 32768
  float* scores = ws + 458752;              // 8160 (pad 8192)
  unsigned short* thb = (unsigned short*)(ws + 466944);  // 32768 bf16

  float* o_prob = out;                      // (B,V)
  float* o_cur  = out + 1024000;            // (B,H)
  float* o_th   = out + 1056768;            // (B,H)
  float* o_ctx  = out + 1089536;            // (B,H)

  k_gates   <<<dim3(768),  dim3(64),  0, stream>>>(wi, lh, thid, emb, Wih, Whh, pgates);
  k_cell    <<<dim3(128),  dim3(256), 0, stream>>>(pgates, bih, bhh, wi, lh, cur, o_cur);
  k_scores  <<<dim3(2040), dim3(256), 0, stream>>>(cur, seq, tree, nn, scores);
  k_context <<<dim3(512),  dim3(256), 0, stream>>>(scores, seq, tree, nn, ctx, o_ctx);
  k_comb    <<<dim3(64),   dim3(256), 0, stream>>>(Wcomb, cur, ctx, bcomb, o_th, thb);
  k_wout    <<<dim3(500),  dim3(256), 0, stream>>>(Wout, thb, o_prob);
}